// Round 6
// baseline (88.381 us; speedup 1.0000x reference)
//
#include <hip/hip_runtime.h>

// out[n,m] = exp(i1[n]·i2[m] - ||i1[n]||^2/2 - ||i2[m]||^2/2), N=M=4096, D=32, f32.
// R3 lesson: kernel < 44 us (absent from top-5); dur_us carries ~57 us harness
// reset overhead. Kernel-side cost = phased compute-then-store-burst.
// R4: 2 tiles/block (shared A panel, double-buffered B); tile0 stores drain
// under tile1 compute; raw s_barrier with lgkmcnt-only (NO vmcnt drain).
// R5/R6: broker timeouts — resubmitting identical kernel.

#define D 32
#define BT 128          // tile edge
#define LDT 132         // LDS row stride (pad 4: bank rotate, 16B-aligned rows)

__global__ __launch_bounds__(256) void rbf_pipe_kernel(
    const float* __restrict__ A,   // [N][32]
    const float* __restrict__ B,   // [M][32]
    float* __restrict__ out,       // [N][M]
    int M, int colpairs)
{
    __shared__ float sA[D][LDT];        // transposed A panel (reused by both tiles)
    __shared__ float sB[2][D][LDT];     // double-buffered B tiles
    __shared__ float hnA[BT];
    __shared__ float hnB[2][BT];

    const int tid = threadIdx.x;
    const int b   = blockIdx.x;
    const int rr_ = b / colpairs;       // A-panel index
    const int cp  = b % colpairs;       // column-pair index
    const int brow  = rr_ * BT;
    const int bcol0 = cp * (2 * BT);
    const int bcol1 = bcol0 + BT;

    const float4* gA  = reinterpret_cast<const float4*>(A + (size_t)brow  * D);
    const float4* gB0 = reinterpret_cast<const float4*>(B + (size_t)bcol0 * D);
    const float4* gB1 = reinterpret_cast<const float4*>(B + (size_t)bcol1 * D);

    // ---- stage A and B0 (transposed) ----
    #pragma unroll
    for (int k = 0; k < 4; ++k) {
        const int i   = tid + k * 256;   // 0..1023
        const int row = i >> 3;
        const int d0  = (i & 7) << 2;
        float4 va = gA[i];
        float4 vb = gB0[i];
        sA[d0+0][row] = va.x; sA[d0+1][row] = va.y;
        sA[d0+2][row] = va.z; sA[d0+3][row] = va.w;
        sB[0][d0+0][row] = vb.x; sB[0][d0+1][row] = vb.y;
        sB[0][d0+2][row] = vb.z; sB[0][d0+3][row] = vb.w;
    }
    __syncthreads();

    if (tid < BT) {
        float s = 0.f;
        #pragma unroll
        for (int d = 0; d < D; ++d) { float v = sA[d][tid]; s += v * v; }
        hnA[tid] = 0.5f * s;
    } else {
        const int rw = tid - BT;
        float s = 0.f;
        #pragma unroll
        for (int d = 0; d < D; ++d) { float v = sB[0][d][rw]; s += v * v; }
        hnB[0][rw] = 0.5f * s;
    }
    __syncthreads();

    const int g   = tid >> 4;
    const int c   = tid & 15;
    const int tr  = g * 8;
    const int tc0 = c * 4;
    const int tc1 = c * 4 + 64;

    // prefetch B1 into registers; lands during tile0 compute
    float4 pb[4];
    #pragma unroll
    for (int k = 0; k < 4; ++k) pb[k] = gB1[tid + k * 256];

    auto do_tile = [&](const float (*sBt)[LDT], const float* hnBt, int bcolt) {
        float acc[8][8];
        #pragma unroll
        for (int i = 0; i < 8; ++i)
            #pragma unroll
            for (int j = 0; j < 8; ++j) acc[i][j] = 0.f;

        #pragma unroll 4
        for (int d = 0; d < D; ++d) {
            const float4 a0 = *reinterpret_cast<const float4*>(&sA[d][tr]);
            const float4 a1 = *reinterpret_cast<const float4*>(&sA[d][tr + 4]);
            const float4 b0 = *reinterpret_cast<const float4*>(&sBt[d][tc0]);
            const float4 b1 = *reinterpret_cast<const float4*>(&sBt[d][tc1]);
            const float av[8] = {a0.x, a0.y, a0.z, a0.w, a1.x, a1.y, a1.z, a1.w};
            const float bv[8] = {b0.x, b0.y, b0.z, b0.w, b1.x, b1.y, b1.z, b1.w};
            #pragma unroll
            for (int i = 0; i < 8; ++i)
                #pragma unroll
                for (int j = 0; j < 8; ++j)
                    acc[i][j] += av[i] * bv[j];
        }

        float hnb[8];
        #pragma unroll
        for (int j = 0; j < 4; ++j) { hnb[j] = hnBt[tc0 + j]; hnb[j + 4] = hnBt[tc1 + j]; }

        #pragma unroll
        for (int i = 0; i < 8; ++i) {
            const float h = hnA[tr + i];
            float4 o0, o1;
            o0.x = __expf(acc[i][0] - h - hnb[0]);
            o0.y = __expf(acc[i][1] - h - hnb[1]);
            o0.z = __expf(acc[i][2] - h - hnb[2]);
            o0.w = __expf(acc[i][3] - h - hnb[3]);
            o1.x = __expf(acc[i][4] - h - hnb[4]);
            o1.y = __expf(acc[i][5] - h - hnb[5]);
            o1.z = __expf(acc[i][6] - h - hnb[6]);
            o1.w = __expf(acc[i][7] - h - hnb[7]);
            float* rp = out + (size_t)(brow + tr + i) * M + bcolt;
            *reinterpret_cast<float4*>(rp + tc0) = o0;
            *reinterpret_cast<float4*>(rp + tc1) = o1;
        }
    };

    // ---- tile 0: compute + exp + store (stores left in flight) ----
    do_tile(sB[0], hnB[0], bcol0);

    // ---- write B1 from prefetch regs ----
    #pragma unroll
    for (int k = 0; k < 4; ++k) {
        const int i   = tid + k * 256;
        const int row = i >> 3;
        const int d0  = (i & 7) << 2;
        sB[1][d0+0][row] = pb[k].x; sB[1][d0+1][row] = pb[k].y;
        sB[1][d0+2][row] = pb[k].z; sB[1][d0+3][row] = pb[k].w;
    }
    // barrier WITHOUT vmcnt drain: tile0 stores stay in flight
    asm volatile("s_waitcnt lgkmcnt(0)" ::: "memory");
    __builtin_amdgcn_s_barrier();
    asm volatile("" ::: "memory");

    if (tid >= BT) {
        const int rw = tid - BT;
        float s = 0.f;
        #pragma unroll
        for (int d = 0; d < D; ++d) { float v = sB[1][d][rw]; s += v * v; }
        hnB[1][rw] = 0.5f * s;
    }
    asm volatile("s_waitcnt lgkmcnt(0)" ::: "memory");
    __builtin_amdgcn_s_barrier();
    asm volatile("" ::: "memory");

    // ---- tile 1 ----
    do_tile(sB[1], hnB[1], bcol1);
}

extern "C" void kernel_launch(void* const* d_in, const int* in_sizes, int n_in,
                              void* d_out, int out_size, void* d_ws, size_t ws_size,
                              hipStream_t stream) {
    const float* A = (const float*)d_in[0];
    const float* B = (const float*)d_in[1];
    float* out     = (float*)d_out;
    const int N = in_sizes[0] / D;        // 4096
    const int M = in_sizes[1] / D;        // 4096
    const int colpairs = M / (2 * BT);    // 16
    const int nblocks  = (N / BT) * colpairs;  // 512
    rbf_pipe_kernel<<<nblocks, 256, 0, stream>>>(A, B, out, M, colpairs);
}

// Round 8
// 82.102 us; speedup vs baseline: 1.0765x; 1.0765x over previous
//
#include <hip/hip_runtime.h>

// out[n,m] = exp(i1[n]·i2[m] - ||i1[n]||^2/2 - ||i2[m]||^2/2), N=M=4096, D=32, f32.
// R6 lesson: dur_us = ~60us fixed harness fills + ~25-30us kernel. Kernel was at
// the VALU/LDS balance point (LDS 1.5x oversubscribed). R7: MFMA 3-pass hi/lo
// bf16 split (dot = ah·bh + ah·bl + al·bh, f32 accum). D=32 = one K-pass of
// mfma_f32_16x16x32_bf16. Kernel should become write-bound (~12-14us).
// Error budget: missing terms ~3*2^-18|a||b| -> delta_s ~1e-5..5e-5; max out
// ~e^-6 (indep Gaussians) -> absmax ~1e-7 << 4.58e-5 threshold.
// R8: broker timeout on R7 — resubmitting identical kernel.

#define DD 32
#define BT 128
#define KP 40   // ushort row stride: 32 bf16 data + pad; f32 half-norm at slots 32..33

typedef __attribute__((ext_vector_type(8))) short bfrag8;
typedef __attribute__((ext_vector_type(4))) float f32x4;

__device__ __forceinline__ unsigned short f2bf_rn(float f) {
    unsigned u = __builtin_bit_cast(unsigned, f);
    u += 0x7FFFu + ((u >> 16) & 1u);      // round-to-nearest-even (inputs are finite)
    return (unsigned short)(u >> 16);
}
__device__ __forceinline__ float bf2f(unsigned short h) {
    unsigned u = ((unsigned)h) << 16;
    return __builtin_bit_cast(float, u);
}

__global__ __launch_bounds__(256) void rbf_mfma_kernel(
    const float* __restrict__ A,   // [N][32]
    const float* __restrict__ B,   // [M][32]
    float* __restrict__ out,       // [N][M]
    int M)
{
    __shared__ unsigned short sAh[BT][KP];   // 4 x 10 KB = 40 KB total -> 4 blocks/CU
    __shared__ unsigned short sAl[BT][KP];
    __shared__ unsigned short sBh[BT][KP];
    __shared__ unsigned short sBl[BT][KP];

    const int tid  = threadIdx.x;
    const int brow = blockIdx.y * BT;
    const int bcol = blockIdx.x * BT;

    const float4* gA = reinterpret_cast<const float4*>(A + (size_t)brow * DD);
    const float4* gB = reinterpret_cast<const float4*>(B + (size_t)bcol * DD);

    // ---- stage: f32 -> (hi,lo) bf16 split into LDS, row-major [row][d] ----
    #pragma unroll
    for (int k = 0; k < 4; ++k) {
        const int i   = tid + k * 256;   // 0..1023
        const int row = i >> 3;
        const int d0  = (i & 7) << 2;
        float4 va = gA[i], vb = gB[i];
        ushort4 ha, la, hb, lb;
        ha.x = f2bf_rn(va.x); la.x = f2bf_rn(va.x - bf2f(ha.x));
        ha.y = f2bf_rn(va.y); la.y = f2bf_rn(va.y - bf2f(ha.y));
        ha.z = f2bf_rn(va.z); la.z = f2bf_rn(va.z - bf2f(ha.z));
        ha.w = f2bf_rn(va.w); la.w = f2bf_rn(va.w - bf2f(ha.w));
        hb.x = f2bf_rn(vb.x); lb.x = f2bf_rn(vb.x - bf2f(hb.x));
        hb.y = f2bf_rn(vb.y); lb.y = f2bf_rn(vb.y - bf2f(hb.y));
        hb.z = f2bf_rn(vb.z); lb.z = f2bf_rn(vb.z - bf2f(hb.z));
        hb.w = f2bf_rn(vb.w); lb.w = f2bf_rn(vb.w - bf2f(hb.w));
        *reinterpret_cast<ushort4*>(&sAh[row][d0]) = ha;
        *reinterpret_cast<ushort4*>(&sAl[row][d0]) = la;
        *reinterpret_cast<ushort4*>(&sBh[row][d0]) = hb;
        *reinterpret_cast<ushort4*>(&sBl[row][d0]) = lb;
    }

    // ---- f32 half-norms from global (L1-hot), stashed in the row pad ----
    {
        const int r = tid & 127;
        const float4* src = (tid < 128)
            ? reinterpret_cast<const float4*>(A + (size_t)(brow + r) * DD)
            : reinterpret_cast<const float4*>(B + (size_t)(bcol + r) * DD);
        float s = 0.f;
        #pragma unroll
        for (int q = 0; q < 8; ++q) {
            float4 v = src[q];
            s += v.x * v.x + v.y * v.y + v.z * v.z + v.w * v.w;
        }
        unsigned short* dst = (tid < 128) ? &sAh[r][32] : &sBh[r][32];
        *reinterpret_cast<float*>(dst) = 0.5f * s;   // disjoint bytes vs staged data
    }
    __syncthreads();

    // ---- per-wave MFMA: wave w owns rows [w*32, w*32+32), all 128 cols ----
    const int lane = tid & 63, wid = tid >> 6;
    const int r0 = wid * 32;
    const int lr = lane & 15;        // A-frag row / B-frag col / D col
    const int lg = lane >> 4;        // k-group; D row group
    const int k0 = lg * 8;

    const bfrag8 ah0 = *reinterpret_cast<const bfrag8*>(&sAh[r0 + lr][k0]);
    const bfrag8 al0 = *reinterpret_cast<const bfrag8*>(&sAl[r0 + lr][k0]);
    const bfrag8 ah1 = *reinterpret_cast<const bfrag8*>(&sAh[r0 + 16 + lr][k0]);
    const bfrag8 al1 = *reinterpret_cast<const bfrag8*>(&sAl[r0 + 16 + lr][k0]);

    float hna0[4], hna1[4];
    #pragma unroll
    for (int q = 0; q < 4; ++q) {
        hna0[q] = *reinterpret_cast<const float*>(&sAh[r0 + lg * 4 + q][32]);
        hna1[q] = *reinterpret_cast<const float*>(&sAh[r0 + 16 + lg * 4 + q][32]);
    }

    const size_t orow0 = (size_t)(brow + r0 + lg * 4) * M + bcol;

    #pragma unroll
    for (int c = 0; c < 8; ++c) {
        const int c0 = c * 16;
        const bfrag8 bh = *reinterpret_cast<const bfrag8*>(&sBh[c0 + lr][k0]);
        const bfrag8 bl = *reinterpret_cast<const bfrag8*>(&sBl[c0 + lr][k0]);
        const float hnb = *reinterpret_cast<const float*>(&sBh[c0 + lr][32]);

        f32x4 acc0 = {0.f, 0.f, 0.f, 0.f}, acc1 = {0.f, 0.f, 0.f, 0.f};
        acc0 = __builtin_amdgcn_mfma_f32_16x16x32_bf16(al0, bh, acc0, 0, 0, 0);
        acc1 = __builtin_amdgcn_mfma_f32_16x16x32_bf16(al1, bh, acc1, 0, 0, 0);
        acc0 = __builtin_amdgcn_mfma_f32_16x16x32_bf16(ah0, bl, acc0, 0, 0, 0);
        acc1 = __builtin_amdgcn_mfma_f32_16x16x32_bf16(ah1, bl, acc1, 0, 0, 0);
        acc0 = __builtin_amdgcn_mfma_f32_16x16x32_bf16(ah0, bh, acc0, 0, 0, 0);
        acc1 = __builtin_amdgcn_mfma_f32_16x16x32_bf16(ah1, bh, acc1, 0, 0, 0);

        float* p0 = out + orow0 + c0 + lr;   // D: col = lane&15, row = lg*4 + q
        #pragma unroll
        for (int q = 0; q < 4; ++q) {
            p0[(size_t)q * M]        = __expf(acc0[q] - hna0[q] - hnb);
            p0[(size_t)(q + 16) * M] = __expf(acc1[q] - hna1[q] - hnb);
        }
    }
}

extern "C" void kernel_launch(void* const* d_in, const int* in_sizes, int n_in,
                              void* d_out, int out_size, void* d_ws, size_t ws_size,
                              hipStream_t stream) {
    const float* A = (const float*)d_in[0];
    const float* B = (const float*)d_in[1];
    float* out     = (float*)d_out;
    const int N = in_sizes[0] / DD;   // 4096
    const int M = in_sizes[1] / DD;   // 4096
    dim3 grid(M / BT, N / BT);        // 32 x 32 = 1024 blocks -> 4/CU, single round
    rbf_mfma_kernel<<<grid, 256, 0, stream>>>(A, B, out, M);
}